// Round 7
// baseline (53.429 us; speedup 1.0000x reference)
//
#include <hip/hip_runtime.h>
#include <hip/hip_bf16.h>

#define B_ 8
#define T_ 2048
#define C_ 1024
#define HS_ 64

typedef float f32x4 __attribute__((ext_vector_type(4)));
typedef __bf16 bf16x8 __attribute__((ext_vector_type(8)));
typedef __bf16 bf16x4 __attribute__((ext_vector_type(4)));

// Workspaces:
//  wt[192][1024] bf16: rows 0-63 Wq^T (scaled 1/32), 64-127 Wk^T, 128-191 Wv^T
//  Qf[b*128+qt16][2 half][64 lane][8] : word = Q[qt*16+(lane&15)][half*32+(lane>>4)*8+j]
//  Kf identical mapping. Vf[b*64+kt32][4 ntv][64][8]:
//  word = V[kt32*32+(lane>>4)*8+j][ntv*16+(lane&15)]

// ---------------------------------------------------------------------------
// Kernel 1: W [1024][64] fp32 -> wt [192][1024] bf16 (transposed, q scaled).
// ---------------------------------------------------------------------------
__global__ __launch_bounds__(256) void wt_kernel(const float* __restrict__ Wq,
                                                 const float* __restrict__ Wk,
                                                 const float* __restrict__ Wv,
                                                 __bf16* __restrict__ wt) {
    __shared__ float tile[64][65];
    int mb = blockIdx.x >> 4;
    int k0 = (blockIdx.x & 15) * 64;
    const float* W = (mb == 0) ? Wq : (mb == 1 ? Wk : Wv);
    int c = threadIdx.x & 63;
#pragma unroll
    for (int r = threadIdx.x >> 6; r < 64; r += 4)
        tile[r][c] = W[(size_t)(k0 + r) * 64 + c];
    __syncthreads();
    float scale = (mb == 0) ? 0.03125f : 1.0f;
    int kk = threadIdx.x & 63;
#pragma unroll
    for (int n = threadIdx.x >> 6; n < 64; n += 4)
        wt[(size_t)(mb * 64 + n) * C_ + k0 + kk] = (__bf16)(tile[kk][n] * scale);
}

// ---------------------------------------------------------------------------
// Kernel 2: QKV GEMM. 1024 blocks x 256 thr (4 waves), ~4 blocks/CU.
// Block: 32 rows x 96 cols (n0 = 0 or 96), K-step 64, dual swizzled LDS
// (32KB). XCD-paired bid mapping: both N-halves of the same 32 rows land on
// the same XCD's L2. Wave w: m-tile w&1, nt (w>>1)*3..+2.
// ---------------------------------------------------------------------------
__global__ __launch_bounds__(256, 4) void qkv_kernel(const float* __restrict__ x,
                                                     const __bf16* __restrict__ wt,
                                                     __bf16* __restrict__ qf,
                                                     __bf16* __restrict__ kf,
                                                     __bf16* __restrict__ vf) {
    __shared__ __align__(16) char smem[32768];
    __bf16* xs0 = (__bf16*)smem;               // [32][64] swz, 4KB
    __bf16* xs1 = (__bf16*)(smem + 4096);
    __bf16* ws0 = (__bf16*)(smem + 8192);      // [96][64] swz, 12KB
    __bf16* ws1 = (__bf16*)(smem + 20480);

    const int tid = threadIdx.x;
    const int w = tid >> 6, lane = tid & 63, lq = lane & 15, lg = lane >> 4;
    // bid = g*16 + h*8 + xcd -> m-chunk g*8+xcd ; h = N-half. Pair shares XCD.
    const int bid = blockIdx.x;
    const int m0 = ((bid >> 4) * 8 + (bid & 7)) * 32;
    const int n0 = ((bid >> 3) & 1) * 96;
    const int mt = w & 1;
    const int ntb = (w >> 1) * 3;

    f32x4 acc[3];
#pragma unroll
    for (int i = 0; i < 3; ++i) acc[i] = (f32x4)0.0f;

    const int xrow = tid >> 3, xch = tid & 7;
    float4 xr0, xr1;
    bf16x8 wr[3];

    // prologue: load kt=0, fill buf0
    {
        const float* xp = x + (size_t)(m0 + xrow) * C_ + xch * 8;
        xr0 = *(const float4*)xp;
        xr1 = *(const float4*)(xp + 4);
#pragma unroll
        for (int s = 0; s < 3; ++s) {
            int u = tid + s * 256;
            wr[s] = *(const bf16x8*)(wt + (size_t)(n0 + (u >> 3)) * C_ + (u & 7) * 8);
        }
        bf16x8 xb;
#pragma unroll
        for (int j = 0; j < 4; ++j) { xb[j] = (__bf16)xr0[j]; xb[4 + j] = (__bf16)xr1[j]; }
        *(bf16x8*)(xs0 + xrow * 64 + ((xch ^ (xrow & 7)) * 8)) = xb;
#pragma unroll
        for (int s = 0; s < 3; ++s) {
            int u = tid + s * 256, rw = u >> 3, ch = u & 7;
            *(bf16x8*)(ws0 + rw * 64 + ((ch ^ (rw & 7)) * 8)) = wr[s];
        }
    }

    for (int kt = 0; kt < 16; ++kt) {
        __syncthreads();
        __bf16* xsc = (kt & 1) ? xs1 : xs0;
        __bf16* wsc = (kt & 1) ? ws1 : ws0;
        if (kt < 15) {
            int k0 = (kt + 1) * 64;
            const float* xp = x + (size_t)(m0 + xrow) * C_ + k0 + xch * 8;
            xr0 = *(const float4*)xp;
            xr1 = *(const float4*)(xp + 4);
#pragma unroll
            for (int s = 0; s < 3; ++s) {
                int u = tid + s * 256;
                wr[s] = *(const bf16x8*)(wt + (size_t)(n0 + (u >> 3)) * C_ + k0 + (u & 7) * 8);
            }
        }
#pragma unroll
        for (int ks = 0; ks < 2; ++ks) {
            int r = mt * 16 + lq;
            bf16x8 a = *(const bf16x8*)(xsc + r * 64 + (((ks * 4 + lg) ^ (r & 7)) * 8));
#pragma unroll
            for (int i = 0; i < 3; ++i) {
                int rw = (ntb + i) * 16 + lq;
                bf16x8 b = *(const bf16x8*)(wsc + rw * 64 + (((ks * 4 + lg) ^ (rw & 7)) * 8));
                acc[i] = __builtin_amdgcn_mfma_f32_16x16x32_bf16(a, b, acc[i], 0, 0, 0);
            }
        }
        if (kt < 15) {
            __bf16* xsn = (kt & 1) ? xs0 : xs1;
            __bf16* wsn = (kt & 1) ? ws0 : ws1;
            bf16x8 xb;
#pragma unroll
            for (int j = 0; j < 4; ++j) { xb[j] = (__bf16)xr0[j]; xb[4 + j] = (__bf16)xr1[j]; }
            *(bf16x8*)(xsn + xrow * 64 + ((xch ^ (xrow & 7)) * 8)) = xb;
#pragma unroll
            for (int s = 0; s < 3; ++s) {
                int u = tid + s * 256, rw = u >> 3, ch = u & 7;
                *(bf16x8*)(wsn + rw * 64 + ((ch ^ (rw & 7)) * 8)) = wr[s];
            }
        }
    }
    __syncthreads();

    // epilogue: acc -> obuf [32][104] -> fragment stores
    __bf16(*obuf)[104] = (__bf16(*)[104])smem;
#pragma unroll
    for (int i = 0; i < 3; ++i)
#pragma unroll
        for (int r = 0; r < 4; ++r)
            obuf[mt * 16 + lg * 4 + r][(ntb + i) * 16 + lq] = (__bf16)acc[i][r];
    __syncthreads();

    if (n0 == 0) {
        // local cols 0-63 = q halves, 64-95 = k half 0
        int mg = w & 1, hf = w >> 1;
        size_t qt16 = (size_t)(m0 >> 4) + mg;
        bf16x8 vq = *(const bf16x8*)&obuf[mg * 16 + lq][hf * 32 + lg * 8];
        *(bf16x8*)(qf + ((qt16 * 2 + hf) * 64 + lane) * 8) = vq;
        if (w < 2) {
            bf16x8 vk = *(const bf16x8*)&obuf[w * 16 + lq][64 + lg * 8];
            *(bf16x8*)(kf + (((size_t)(m0 >> 4) + w) * 2 * 64 + lane) * 8) = vk;
        }
    } else {
        // local cols 0-31 = k half 1, 32-95 = v
        if (w < 2) {
            bf16x8 vk = *(const bf16x8*)&obuf[w * 16 + lq][lg * 8];
            *(bf16x8*)(kf + ((((size_t)(m0 >> 4) + w) * 2 + 1) * 64 + lane) * 8) = vk;
        }
        bf16x8 vv;
#pragma unroll
        for (int j = 0; j < 8; ++j)
            vv[j] = obuf[lg * 8 + j][32 + w * 16 + lq];
        size_t kt32 = (size_t)(m0 >> 5);
        *(bf16x8*)(vf + ((kt32 * 4 + w) * 64 + lane) * 8) = vv;
    }
}

// ---------------------------------------------------------------------------
// Kernel 3: causal flash attention, Q32 per block, swapped QK^T, KVBLK=64.
// 512 blocks x 4 waves; waves split 64-key tiles round-robin (kt += 4).
// K-frags amortized over 2 query sub-tiles; P-staging overlaid on the
// per-wave combine buffer; two-phase cross-wave flash-combine.
// ---------------------------------------------------------------------------
__global__ __launch_bounds__(256, 3) void attn_kernel(const __bf16* __restrict__ qf,
                                                      const __bf16* __restrict__ kf,
                                                      const __bf16* __restrict__ vf,
                                                      float* __restrict__ out) {
    // per-wave union: plds [32][72] bf16 (4608B)  /  olds [16][64] f32 (4096B)
    __shared__ __align__(16) char smem[4 * 4608];
    __shared__ float mlds[4][16], llds[4][16];

    int w    = threadIdx.x >> 6;
    int lane = threadIdx.x & 63;
    int lq = lane & 15, lg = lane >> 4;

    int b  = blockIdx.x & 7;                   // batch -> XCD affinity
    int q0 = (63 - (blockIdx.x >> 3)) * 32;    // heavy tiles first

    __bf16* pw = (__bf16*)(smem + w * 4608);

    // Q B-frags for both 16-query sub-tiles
    bf16x8 bq[2][2];
#pragma unroll
    for (int qs = 0; qs < 2; ++qs)
#pragma unroll
        for (int hf = 0; hf < 2; ++hf)
            bq[qs][hf] = *(const bf16x8*)(qf +
                ((((size_t)b * 128 + (q0 >> 4) + qs) * 2 + hf) * 64 + lane) * 8);

    f32x4 o[2][4];
#pragma unroll
    for (int qs = 0; qs < 2; ++qs)
#pragma unroll
        for (int nt = 0; nt < 4; ++nt) o[qs][nt] = (f32x4)0.0f;
    float m_s[2] = {-1e30f, -1e30f}, l_s[2] = {0.f, 0.f};

    int ntiles = (q0 + 95) >> 6;   // ceil((q0+32)/64)
    for (int kt = w; kt < ntiles; kt += 4) {
        int s0 = kt * 64;
        f32x4 s[2][4];
        // S^T = K Q^T : A = K frags (shared by both q sub-tiles), B = Q
        __builtin_amdgcn_s_setprio(1);
#pragma unroll
        for (int ct = 0; ct < 4; ++ct) {
            size_t kbase = ((size_t)b * 128 + (s0 >> 4) + ct) * 2;
            bf16x8 k0 = *(const bf16x8*)(kf + ((kbase + 0) * 64 + lane) * 8);
            bf16x8 k1 = *(const bf16x8*)(kf + ((kbase + 1) * 64 + lane) * 8);
#pragma unroll
            for (int qs = 0; qs < 2; ++qs) {
                f32x4 a = (f32x4)0.0f;
                a = __builtin_amdgcn_mfma_f32_16x16x32_bf16(k0, bq[qs][0], a, 0, 0, 0);
                a = __builtin_amdgcn_mfma_f32_16x16x32_bf16(k1, bq[qs][1], a, 0, 0, 0);
                s[qs][ct] = a;
            }
        }
        __builtin_amdgcn_s_setprio(0);
        // causal mask: key = s0+ct*16+lg*4+r vs query = q0+qs*16+lq
        if (s0 + 63 > q0) {
#pragma unroll
            for (int qs = 0; qs < 2; ++qs)
#pragma unroll
                for (int ct = 0; ct < 4; ++ct)
#pragma unroll
                    for (int r = 0; r < 4; ++r)
                        if (s0 + ct * 16 + lg * 4 + r > q0 + qs * 16 + lq)
                            s[qs][ct][r] = -1e30f;
        }
        // online softmax per sub-tile (16 in-reg scores + 2 shfl combine)
        float al2[2];
#pragma unroll
        for (int qs = 0; qs < 2; ++qs) {
            float pm = -1e30f;
#pragma unroll
            for (int ct = 0; ct < 4; ++ct)
#pragma unroll
                for (int r = 0; r < 4; ++r) pm = fmaxf(pm, s[qs][ct][r]);
            pm = fmaxf(pm, __shfl_xor(pm, 16));
            pm = fmaxf(pm, __shfl_xor(pm, 32));
            float mn = fmaxf(m_s[qs], pm);
            float al = __expf(m_s[qs] - mn);
            m_s[qs] = mn;
            float rs = 0.f;
#pragma unroll
            for (int ct = 0; ct < 4; ++ct)
#pragma unroll
                for (int r = 0; r < 4; ++r) {
                    float p = __expf(s[qs][ct][r] - mn);
                    s[qs][ct][r] = p;
                    rs += p;
                }
            rs += __shfl_xor(rs, 16);
            rs += __shfl_xor(rs, 32);
            l_s[qs] = l_s[qs] * al + rs;
            al2[qs] = al;
        }
#pragma unroll
        for (int qs = 0; qs < 2; ++qs) {
            float alr[4];
#pragma unroll
            for (int r = 0; r < 4; ++r) alr[r] = __shfl(al2[qs], lg * 4 + r);
#pragma unroll
            for (int nt = 0; nt < 4; ++nt)
#pragma unroll
                for (int r = 0; r < 4; ++r) o[qs][nt][r] *= alr[r];
        }
        // P -> LDS: row = qs*16+lq (query), cols = 64 keys
#pragma unroll
        for (int qs = 0; qs < 2; ++qs)
#pragma unroll
            for (int ct = 0; ct < 4; ++ct) {
                bf16x4 qv;
#pragma unroll
                for (int r = 0; r < 4; ++r) qv[r] = (__bf16)s[qs][ct][r];
                *(bf16x4*)&pw[(qs * 16 + lq) * 72 + ct * 16 + lg * 4] = qv;
            }
        asm volatile("" ::: "memory");
        // V frags (shared by both q sub-tiles)
        bf16x8 bv[2][4];
#pragma unroll
        for (int ks = 0; ks < 2; ++ks)
#pragma unroll
            for (int nt = 0; nt < 4; ++nt)
                bv[ks][nt] = *(const bf16x8*)(vf +
                    (((size_t)(b * 64 + (s0 >> 5) + ks) * 4 + nt) * 64 + lane) * 8);
        __builtin_amdgcn_s_setprio(1);
#pragma unroll
        for (int qs = 0; qs < 2; ++qs) {
            bf16x8 pa0 = *(const bf16x8*)&pw[(qs * 16 + lq) * 72 + lg * 8];
            bf16x8 pa1 = *(const bf16x8*)&pw[(qs * 16 + lq) * 72 + 32 + lg * 8];
#pragma unroll
            for (int nt = 0; nt < 4; ++nt) {
                o[qs][nt] = __builtin_amdgcn_mfma_f32_16x16x32_bf16(pa0, bv[0][nt], o[qs][nt], 0, 0, 0);
                o[qs][nt] = __builtin_amdgcn_mfma_f32_16x16x32_bf16(pa1, bv[1][nt], o[qs][nt], 0, 0, 0);
            }
        }
        __builtin_amdgcn_s_setprio(0);
    }

    // two-phase cross-wave flash-combine (olds overlays plds per wave)
    float* olds_w = (float*)(smem + w * 4608);
#pragma unroll
    for (int qs = 0; qs < 2; ++qs) {
        __syncthreads();   // qs0: waves done with plds; qs1: combine reads done
#pragma unroll
        for (int nt = 0; nt < 4; ++nt)
#pragma unroll
            for (int r = 0; r < 4; ++r)
                olds_w[(lg * 4 + r) * 64 + nt * 16 + lq] = o[qs][nt][r];
        if (lg == 0) {
            mlds[w][lq] = m_s[qs];
            llds[w][lq] = l_s[qs];
        }
        __syncthreads();
        int row = threadIdx.x >> 4;
        int c4  = (threadIdx.x & 15) * 4;
        float M = -1e30f;
#pragma unroll
        for (int w2 = 0; w2 < 4; ++w2) M = fmaxf(M, mlds[w2][row]);
        float L = 0.f;
        f32x4 oa = (f32x4)0.0f;
#pragma unroll
        for (int w2 = 0; w2 < 4; ++w2) {
            float sc = __expf(mlds[w2][row] - M);
            L += sc * llds[w2][row];
            const float* op = (const float*)(smem + w2 * 4608) + row * 64 + c4;
#pragma unroll
            for (int j = 0; j < 4; ++j) oa[j] += sc * op[j];
        }
        float inv = 1.0f / L;
        float4 st;
        st.x = oa[0] * inv; st.y = oa[1] * inv; st.z = oa[2] * inv; st.w = oa[3] * inv;
        *(float4*)(out + ((size_t)b * T_ + q0 + qs * 16 + row) * HS_ + c4) = st;
    }
}

extern "C" void kernel_launch(void* const* d_in, const int* in_sizes, int n_in,
                              void* d_out, int out_size, void* d_ws, size_t ws_size,
                              hipStream_t stream) {
    const float* x  = (const float*)d_in[0];
    const float* Wq = (const float*)d_in[1];
    const float* Wk = (const float*)d_in[2];
    const float* Wv = (const float*)d_in[3];
    char* ws = (char*)d_ws;
    __bf16* wt = (__bf16*)ws;                     // 393216 B
    __bf16* qf = (__bf16*)(ws + 393216);          // 2 MB
    __bf16* kf = (__bf16*)(ws + 2490368);         // 2 MB
    __bf16* vf = (__bf16*)(ws + 4587520);         // 2 MB
    float* out = (float*)d_out;

    wt_kernel<<<dim3(48), dim3(256), 0, stream>>>(Wq, Wk, Wv, wt);
    qkv_kernel<<<dim3(1024), dim3(256), 0, stream>>>(x, wt, qf, kf, vf);
    attn_kernel<<<dim3(512), dim3(256), 0, stream>>>(qf, kf, vf, out);
}

// Round 8
// 41.240 us; speedup vs baseline: 1.2955x; 1.2955x over previous
//
#include <hip/hip_runtime.h>
#include <hip/hip_bf16.h>

#define B_ 8
#define T_ 2048
#define C_ 1024
#define HS_ 64

typedef float f32x4 __attribute__((ext_vector_type(4)));
typedef __bf16 bf16x8 __attribute__((ext_vector_type(8)));
typedef __bf16 bf16x4 __attribute__((ext_vector_type(4)));

// Workspaces:
//  wt[192][1024] bf16: rows 0-63 Wq^T (scaled 1/32), 64-127 Wk^T, 128-191 Wv^T
//  Qf[b*128+qt16][2 half][64 lane][8] : word = Q[qt*16+(lane&15)][half*32+(lane>>4)*8+j]
//  Kf identical mapping. Vf[b*64+kt32][4 ntv][64][8]:
//  word = V[kt32*32+(lane>>4)*8+j][ntv*16+(lane&15)]

// ---------------------------------------------------------------------------
// Kernel 1: W [1024][64] fp32 -> wt [192][1024] bf16 (transposed, q scaled).
// (r5-exact, known good)
// ---------------------------------------------------------------------------
__global__ __launch_bounds__(256) void wt_kernel(const float* __restrict__ Wq,
                                                 const float* __restrict__ Wk,
                                                 const float* __restrict__ Wv,
                                                 __bf16* __restrict__ wt) {
    __shared__ float tile[64][65];
    int mb = blockIdx.x >> 4;
    int k0 = (blockIdx.x & 15) * 64;
    const float* W = (mb == 0) ? Wq : (mb == 1 ? Wk : Wv);
    int c = threadIdx.x & 63;
#pragma unroll
    for (int r = threadIdx.x >> 6; r < 64; r += 4)
        tile[r][c] = W[(size_t)(k0 + r) * 64 + c];
    __syncthreads();
    float scale = (mb == 0) ? 0.03125f : 1.0f;
    int kk = threadIdx.x & 63;
#pragma unroll
    for (int n = threadIdx.x >> 6; n < 64; n += 4)
        wt[(size_t)(mb * 64 + n) * C_ + k0 + kk] = (__bf16)(tile[kk][n] * scale);
}

// ---------------------------------------------------------------------------
// Kernel 2: QKV GEMM (r5-exact, known good). 512 blocks x 512 thr (8 waves).
// Block: 32 rows x 192 cols, K-step 64, dual swizzled LDS staging (56KB).
// ---------------------------------------------------------------------------
__global__ __launch_bounds__(512) void qkv_kernel(const float* __restrict__ x,
                                                  const __bf16* __restrict__ wt,
                                                  __bf16* __restrict__ qf,
                                                  __bf16* __restrict__ kf,
                                                  __bf16* __restrict__ vf) {
    __shared__ __align__(16) char smem[57344];
    __bf16* xs0 = (__bf16*)smem;               // [32][64] swz, 4KB
    __bf16* xs1 = (__bf16*)(smem + 4096);
    __bf16* ws0 = (__bf16*)(smem + 8192);      // [192][64] swz, 24KB
    __bf16* ws1 = (__bf16*)(smem + 32768);

    const int tid = threadIdx.x;
    const int w = tid >> 6, lane = tid & 63, lq = lane & 15, lg = lane >> 4;
    const int m0 = blockIdx.x * 32;
    const int mt = w & 1;
    const int ntb = (w >> 1) * 3;

    f32x4 acc[3];
#pragma unroll
    for (int i = 0; i < 3; ++i) acc[i] = (f32x4)0.0f;

    const int xrow = tid >> 3, xch = tid & 7;
    float4 xr0, xr1;
    bf16x8 wr[3];

    if (tid < 256) {
        const float* xp = x + (size_t)(m0 + xrow) * C_ + xch * 8;
        xr0 = *(const float4*)xp;
        xr1 = *(const float4*)(xp + 4);
    }
#pragma unroll
    for (int s = 0; s < 3; ++s) {
        int u = tid + s * 512;
        wr[s] = *(const bf16x8*)(wt + (size_t)(u >> 3) * C_ + (u & 7) * 8);
    }
    if (tid < 256) {
        bf16x8 xb;
#pragma unroll
        for (int j = 0; j < 4; ++j) { xb[j] = (__bf16)xr0[j]; xb[4 + j] = (__bf16)xr1[j]; }
        *(bf16x8*)(xs0 + xrow * 64 + ((xch ^ (xrow & 7)) * 8)) = xb;
    }
#pragma unroll
    for (int s = 0; s < 3; ++s) {
        int u = tid + s * 512, rw = u >> 3, ch = u & 7;
        *(bf16x8*)(ws0 + rw * 64 + ((ch ^ (rw & 7)) * 8)) = wr[s];
    }

    for (int kt = 0; kt < 16; ++kt) {
        __syncthreads();
        __bf16* xsc = (kt & 1) ? xs1 : xs0;
        __bf16* wsc = (kt & 1) ? ws1 : ws0;
        if (kt < 15) {
            int k0 = (kt + 1) * 64;
            if (tid < 256) {
                const float* xp = x + (size_t)(m0 + xrow) * C_ + k0 + xch * 8;
                xr0 = *(const float4*)xp;
                xr1 = *(const float4*)(xp + 4);
            }
#pragma unroll
            for (int s = 0; s < 3; ++s) {
                int u = tid + s * 512;
                wr[s] = *(const bf16x8*)(wt + (size_t)(u >> 3) * C_ + k0 + (u & 7) * 8);
            }
        }
#pragma unroll
        for (int ks = 0; ks < 2; ++ks) {
            int r = mt * 16 + lq;
            bf16x8 a = *(const bf16x8*)(xsc + r * 64 + (((ks * 4 + lg) ^ (r & 7)) * 8));
#pragma unroll
            for (int i = 0; i < 3; ++i) {
                int rw = (ntb + i) * 16 + lq;
                bf16x8 b = *(const bf16x8*)(wsc + rw * 64 + (((ks * 4 + lg) ^ (rw & 7)) * 8));
                acc[i] = __builtin_amdgcn_mfma_f32_16x16x32_bf16(a, b, acc[i], 0, 0, 0);
            }
        }
        if (kt < 15) {
            __bf16* xsn = (kt & 1) ? xs0 : xs1;
            __bf16* wsn = (kt & 1) ? ws0 : ws1;
            if (tid < 256) {
                bf16x8 xb;
#pragma unroll
                for (int j = 0; j < 4; ++j) { xb[j] = (__bf16)xr0[j]; xb[4 + j] = (__bf16)xr1[j]; }
                *(bf16x8*)(xsn + xrow * 64 + ((xch ^ (xrow & 7)) * 8)) = xb;
            }
#pragma unroll
            for (int s = 0; s < 3; ++s) {
                int u = tid + s * 512, rw = u >> 3, ch = u & 7;
                *(bf16x8*)(wsn + rw * 64 + ((ch ^ (rw & 7)) * 8)) = wr[s];
            }
        }
    }
    __syncthreads();

    __bf16(*obuf)[208] = (__bf16(*)[208])smem;
#pragma unroll
    for (int i = 0; i < 3; ++i)
#pragma unroll
        for (int r = 0; r < 4; ++r)
            obuf[mt * 16 + lg * 4 + r][(ntb + i) * 16 + lq] = (__bf16)acc[i][r];
    __syncthreads();

    if (w < 4) {
        int mg = w & 1, half = w >> 1;
        size_t qt16 = (size_t)(m0 >> 4) + mg;
        bf16x8 vq = *(const bf16x8*)&obuf[mg * 16 + lq][half * 32 + lg * 8];
        bf16x8 vk = *(const bf16x8*)&obuf[mg * 16 + lq][64 + half * 32 + lg * 8];
        *(bf16x8*)(qf + ((qt16 * 2 + half) * 64 + lane) * 8) = vq;
        *(bf16x8*)(kf + ((qt16 * 2 + half) * 64 + lane) * 8) = vk;
    } else {
        int ntv = w - 4;
        bf16x8 vv;
#pragma unroll
        for (int j = 0; j < 8; ++j)
            vv[j] = obuf[lg * 8 + j][128 + ntv * 16 + lq];
        size_t kt32 = (size_t)(m0 >> 5);
        *(bf16x8*)(vf + ((kt32 * 4 + ntv) * 64 + lane) * 8) = vv;
    }
}

// ---------------------------------------------------------------------------
// Kernel 3: causal flash attention. 512 blocks x 8 waves; Q32 per block via
// WAVE-PAIRING: waves 0-3 own queries [q0,q0+16), waves 4-7 own
// [q0+16,q0+32); kt round-robin += 4 within each half. Swapped QK^T,
// KVBLK=64, defer-max (THR=0, exact), V-prefetch before softmax,
// flash-combine across each 4-wave half.
// ---------------------------------------------------------------------------
__global__ __launch_bounds__(512, 4) void attn_kernel(const __bf16* __restrict__ qf,
                                                      const __bf16* __restrict__ kf,
                                                      const __bf16* __restrict__ vf,
                                                      float* __restrict__ out) {
    __shared__ float olds[8][16][64];                    // 32 KB
    __shared__ float mlds[8][16], llds[8][16];           // 1 KB
    __shared__ __align__(16) __bf16 plds[8][16 * 72];    // 18 KB

    int w    = threadIdx.x >> 6;
    int lane = threadIdx.x & 63;
    int lq = lane & 15, lg = lane >> 4;

    int b  = blockIdx.x & 7;                   // batch -> XCD affinity
    int q0 = (63 - (blockIdx.x >> 3)) * 32;    // heavy tiles first
    int qs = w >> 2;                           // query sub-tile of this wave
    int wk = w & 3;                            // kt round-robin slot
    int qt = q0 + qs * 16;

    size_t qbase = ((size_t)b * 128 + (qt >> 4)) * 2;
    bf16x8 aq0 = *(const bf16x8*)(qf + ((qbase + 0) * 64 + lane) * 8);
    bf16x8 aq1 = *(const bf16x8*)(qf + ((qbase + 1) * 64 + lane) * 8);

    f32x4 o[4];
#pragma unroll
    for (int nt = 0; nt < 4; ++nt) o[nt] = (f32x4)0.0f;
    float m_s = -1e30f, l_s = 0.f;

    __bf16* pw = &plds[w][0];

    int ntiles = (qt + 79) >> 6;   // ceil((qt+16)/64)
    for (int kt = wk; kt < ntiles; kt += 4) {
        int s0 = kt * 64;
        // S^T = K Q^T : col = query (lq), row = key
        f32x4 s[4];
        __builtin_amdgcn_s_setprio(1);
#pragma unroll
        for (int ct = 0; ct < 4; ++ct) {
            size_t kbase = ((size_t)b * 128 + (s0 >> 4) + ct) * 2;
            bf16x8 k0 = *(const bf16x8*)(kf + ((kbase + 0) * 64 + lane) * 8);
            bf16x8 k1 = *(const bf16x8*)(kf + ((kbase + 1) * 64 + lane) * 8);
            f32x4 a = (f32x4)0.0f;
            a = __builtin_amdgcn_mfma_f32_16x16x32_bf16(k0, aq0, a, 0, 0, 0);
            a = __builtin_amdgcn_mfma_f32_16x16x32_bf16(k1, aq1, a, 0, 0, 0);
            s[ct] = a;
        }
        __builtin_amdgcn_s_setprio(0);
        // causal mask: key = s0+ct*16+lg*4+r vs query = qt+lq
        if (s0 + 63 > qt) {
#pragma unroll
            for (int ct = 0; ct < 4; ++ct)
#pragma unroll
                for (int r = 0; r < 4; ++r)
                    if (s0 + ct * 16 + lg * 4 + r > qt + lq) s[ct][r] = -1e30f;
        }
        // prefetch V fragments (independent of softmax -> hides L2 latency)
        bf16x8 bv[2][4];
#pragma unroll
        for (int ks = 0; ks < 2; ++ks)
#pragma unroll
            for (int nt = 0; nt < 4; ++nt)
                bv[ks][nt] = *(const bf16x8*)(vf +
                    (((size_t)(b * 64 + (s0 >> 5) + ks) * 4 + nt) * 64 + lane) * 8);
        // softmax with defer-max (THR=0: exact)
        float pm = -1e30f;
#pragma unroll
        for (int ct = 0; ct < 4; ++ct)
#pragma unroll
            for (int r = 0; r < 4; ++r) pm = fmaxf(pm, s[ct][r]);
        pm = fmaxf(pm, __shfl_xor(pm, 16));
        pm = fmaxf(pm, __shfl_xor(pm, 32));
        bool need = __any(pm > m_s);
        float al = 1.0f;
        if (need) {
            float mn = fmaxf(m_s, pm);
            al = __expf(m_s - mn);
            m_s = mn;
        }
        float rs = 0.f;
        f32x4 p[4];
#pragma unroll
        for (int ct = 0; ct < 4; ++ct)
#pragma unroll
            for (int r = 0; r < 4; ++r) {
                p[ct][r] = __expf(s[ct][r] - m_s);
                rs += p[ct][r];
            }
        rs += __shfl_xor(rs, 16);
        rs += __shfl_xor(rs, 32);
        if (need) {
            l_s = l_s * al + rs;
            float alr[4];
#pragma unroll
            for (int r = 0; r < 4; ++r) alr[r] = __shfl(al, lg * 4 + r);
#pragma unroll
            for (int nt = 0; nt < 4; ++nt)
#pragma unroll
                for (int r = 0; r < 4; ++r) o[nt][r] *= alr[r];
        } else {
            l_s += rs;
        }
        // P -> LDS: row = query lq, cols = 64 keys
#pragma unroll
        for (int ct = 0; ct < 4; ++ct) {
            bf16x4 qv;
#pragma unroll
            for (int r = 0; r < 4; ++r) qv[r] = (__bf16)p[ct][r];
            *(bf16x4*)&pw[lq * 72 + ct * 16 + lg * 4] = qv;
        }
        asm volatile("" ::: "memory");
        bf16x8 pa0 = *(const bf16x8*)&pw[lq * 72 + lg * 8];
        bf16x8 pa1 = *(const bf16x8*)&pw[lq * 72 + 32 + lg * 8];
        __builtin_amdgcn_s_setprio(1);
#pragma unroll
        for (int nt = 0; nt < 4; ++nt) {
            o[nt] = __builtin_amdgcn_mfma_f32_16x16x32_bf16(pa0, bv[0][nt], o[nt], 0, 0, 0);
            o[nt] = __builtin_amdgcn_mfma_f32_16x16x32_bf16(pa1, bv[1][nt], o[nt], 0, 0, 0);
        }
        __builtin_amdgcn_s_setprio(0);
    }

    // stash per-wave partials
    asm volatile("" ::: "memory");
#pragma unroll
    for (int nt = 0; nt < 4; ++nt)
#pragma unroll
        for (int r = 0; r < 4; ++r)
            olds[w][lg * 4 + r][nt * 16 + lq] = o[nt][r];
    if (lg == 0) {
        mlds[w][lq] = m_s;
        llds[w][lq] = l_s;
    }
    __syncthreads();

    // flash-combine: 512 threads cover 32 rows x 16 col-quads; each half-row
    // combines its own 4 waves.
    int row = threadIdx.x >> 4;          // 0..31 (query within q-block)
    int c4  = (threadIdx.x & 15) * 4;
    int wb  = (row >> 4) * 4;            // wave base: 0 or 4
    int r16 = row & 15;
    float M = -1e30f;
#pragma unroll
    for (int w2 = 0; w2 < 4; ++w2) M = fmaxf(M, mlds[wb + w2][r16]);
    float L = 0.f;
    f32x4 oa = (f32x4)0.0f;
#pragma unroll
    for (int w2 = 0; w2 < 4; ++w2) {
        float sc = __expf(mlds[wb + w2][r16] - M);
        L += sc * llds[wb + w2][r16];
        const float* op = &olds[wb + w2][r16][c4];
#pragma unroll
        for (int j = 0; j < 4; ++j) oa[j] += sc * op[j];
    }
    float inv = 1.0f / L;
    float4 st;
    st.x = oa[0] * inv; st.y = oa[1] * inv; st.z = oa[2] * inv; st.w = oa[3] * inv;
    *(float4*)(out + ((size_t)b * T_ + q0 + row) * HS_ + c4) = st;
}

extern "C" void kernel_launch(void* const* d_in, const int* in_sizes, int n_in,
                              void* d_out, int out_size, void* d_ws, size_t ws_size,
                              hipStream_t stream) {
    const float* x  = (const float*)d_in[0];
    const float* Wq = (const float*)d_in[1];
    const float* Wk = (const float*)d_in[2];
    const float* Wv = (const float*)d_in[3];
    char* ws = (char*)d_ws;
    __bf16* wt = (__bf16*)ws;                     // 393216 B
    __bf16* qf = (__bf16*)(ws + 393216);          // 2 MB
    __bf16* kf = (__bf16*)(ws + 2490368);         // 2 MB
    __bf16* vf = (__bf16*)(ws + 4587520);         // 2 MB
    float* out = (float*)d_out;

    wt_kernel<<<dim3(48), dim3(256), 0, stream>>>(Wq, Wk, Wv, wt);
    qkv_kernel<<<dim3(512), dim3(512), 0, stream>>>(x, wt, qf, kf, vf);
    attn_kernel<<<dim3(512), dim3(512), 0, stream>>>(qf, kf, vf, out);
}

// Round 9
// 38.909 us; speedup vs baseline: 1.3732x; 1.0599x over previous
//
#include <hip/hip_runtime.h>
#include <hip/hip_bf16.h>

#define B_ 8
#define T_ 2048
#define C_ 1024
#define HS_ 64

typedef float f32x4 __attribute__((ext_vector_type(4)));
typedef __bf16 bf16x8 __attribute__((ext_vector_type(8)));
typedef __bf16 bf16x4 __attribute__((ext_vector_type(4)));

__device__ __forceinline__ void gld_lds16(const void* g, void* l) {
    __builtin_amdgcn_global_load_lds(
        (const __attribute__((address_space(1))) void*)g,
        (__attribute__((address_space(3))) void*)l, 16, 0, 0);
}

// Workspaces:
//  wt[192][1024] bf16, PRE-SWIZZLED per 64-col k-tile: chunk c (16B) of row
//  rw holds original chunk c^(rw&7). Linear global_load_lds then lands the
//  swizzled image in LDS, and reads use chunk^(rw&7) as before (rule #21:
//  source permutation == read permutation). Rows 0-63 Wq^T (scaled 1/32),
//  64-127 Wk^T, 128-191 Wv^T.
//  Qf[b*128+qt16][2 half][64 lane][8] : word = Q[qt*16+(lane&15)][half*32+(lane>>4)*8+j]
//  Kf identical mapping. Vf[b*64+kt32][4 ntv][64][8]:
//  word = V[kt32*32+(lane>>4)*8+j][ntv*16+(lane&15)]

// ---------------------------------------------------------------------------
// Kernel 1: W [1024][64] fp32 -> wt [192][1024] bf16, transposed, q scaled,
// chunk-swizzled within each 64-col k-tile for gload_lds staging.
// ---------------------------------------------------------------------------
__global__ __launch_bounds__(256) void wt_kernel(const float* __restrict__ Wq,
                                                 const float* __restrict__ Wk,
                                                 const float* __restrict__ Wv,
                                                 __bf16* __restrict__ wt) {
    __shared__ float tile[64][65];
    int mb = blockIdx.x >> 4;
    int k0 = (blockIdx.x & 15) * 64;
    const float* W = (mb == 0) ? Wq : (mb == 1 ? Wk : Wv);
    int c = threadIdx.x & 63;
#pragma unroll
    for (int r = threadIdx.x >> 6; r < 64; r += 4)
        tile[r][c] = W[(size_t)(k0 + r) * 64 + c];
    __syncthreads();
    float scale = (mb == 0) ? 0.03125f : 1.0f;
    int kk = threadIdx.x & 63;
#pragma unroll
    for (int n = threadIdx.x >> 6; n < 64; n += 4) {
        // store chunk (kk>>3)^(row&7) position <- original chunk kk>>3
        int col = (((kk >> 3) ^ (n & 7)) * 8) + (kk & 7);
        wt[(size_t)(mb * 64 + n) * C_ + k0 + col] = (__bf16)(tile[kk][n] * scale);
    }
}

// ---------------------------------------------------------------------------
// Kernel 2: QKV GEMM. 512 blocks x 512 thr (8 waves). Block: 32 rows x 192
// cols, K-step 64. W staged via global_load_lds (async, no VGPR round-trip,
// 3 issues/wave from pre-swizzled wt); x reg-staged fp32->bf16 with swizzled
// ds_write. Double-buffered, one barrier per K-step.
// ---------------------------------------------------------------------------
__global__ __launch_bounds__(512) void qkv_kernel(const float* __restrict__ x,
                                                  const __bf16* __restrict__ wt,
                                                  __bf16* __restrict__ qf,
                                                  __bf16* __restrict__ kf,
                                                  __bf16* __restrict__ vf) {
    __shared__ __align__(16) char smem[57344];
    __bf16* xs0 = (__bf16*)smem;               // [32][64] swz, 4KB
    __bf16* xs1 = (__bf16*)(smem + 4096);
    __bf16* ws0 = (__bf16*)(smem + 8192);      // [192][64] swz, 24KB
    __bf16* ws1 = (__bf16*)(smem + 32768);

    const int tid = threadIdx.x;
    const int w = tid >> 6, lane = tid & 63, lq = lane & 15, lg = lane >> 4;
    const int m0 = blockIdx.x * 32;
    const int mt = w & 1;
    const int ntb = (w >> 1) * 3;

    f32x4 acc[3];
#pragma unroll
    for (int i = 0; i < 3; ++i) acc[i] = (f32x4)0.0f;

    const int xrow = tid >> 3, xch = tid & 7;
    float4 xr0, xr1;
    // W slot for this thread's wave: slot = (w*3+s)*64 + lane
    const int wslot0 = w * 3 * 64 + lane;

    // prologue: stage kt=0 into buf0
    if (tid < 256) {
        const float* xp = x + (size_t)(m0 + xrow) * C_ + xch * 8;
        xr0 = *(const float4*)xp;
        xr1 = *(const float4*)(xp + 4);
    }
#pragma unroll
    for (int s = 0; s < 3; ++s) {
        int slot = wslot0 + s * 64;
        gld_lds16(wt + (size_t)(slot >> 3) * C_ + (slot & 7) * 8,
                  ws0 + (w * 3 + s) * 512);
    }
    if (tid < 256) {
        bf16x8 xb;
#pragma unroll
        for (int j = 0; j < 4; ++j) { xb[j] = (__bf16)xr0[j]; xb[4 + j] = (__bf16)xr1[j]; }
        *(bf16x8*)(xs0 + xrow * 64 + ((xch ^ (xrow & 7)) * 8)) = xb;
    }

    for (int kt = 0; kt < 16; ++kt) {
        __syncthreads();
        __bf16* xsc = (kt & 1) ? xs1 : xs0;
        __bf16* wsc = (kt & 1) ? ws1 : ws0;
        __bf16* xsn = (kt & 1) ? xs0 : xs1;
        __bf16* wsn = (kt & 1) ? ws0 : ws1;
        if (kt < 15) {
            int k0 = (kt + 1) * 64;
            if (tid < 256) {
                const float* xp = x + (size_t)(m0 + xrow) * C_ + k0 + xch * 8;
                xr0 = *(const float4*)xp;
                xr1 = *(const float4*)(xp + 4);
            }
            // async W stage into next buffer (completion enforced by the
            // compiler's vmcnt(0) drain before next iteration's barrier)
#pragma unroll
            for (int s = 0; s < 3; ++s) {
                int slot = wslot0 + s * 64;
                gld_lds16(wt + (size_t)(slot >> 3) * C_ + k0 + (slot & 7) * 8,
                          wsn + (w * 3 + s) * 512);
            }
        }
#pragma unroll
        for (int ks = 0; ks < 2; ++ks) {
            int r = mt * 16 + lq;
            bf16x8 a = *(const bf16x8*)(xsc + r * 64 + (((ks * 4 + lg) ^ (r & 7)) * 8));
#pragma unroll
            for (int i = 0; i < 3; ++i) {
                int rw = (ntb + i) * 16 + lq;
                bf16x8 b = *(const bf16x8*)(wsc + rw * 64 + (((ks * 4 + lg) ^ (rw & 7)) * 8));
                acc[i] = __builtin_amdgcn_mfma_f32_16x16x32_bf16(a, b, acc[i], 0, 0, 0);
            }
        }
        if (kt < 15 && tid < 256) {
            bf16x8 xb;
#pragma unroll
            for (int j = 0; j < 4; ++j) { xb[j] = (__bf16)xr0[j]; xb[4 + j] = (__bf16)xr1[j]; }
            *(bf16x8*)(xsn + xrow * 64 + ((xch ^ (xrow & 7)) * 8)) = xb;
        }
    }
    __syncthreads();

    __bf16(*obuf)[208] = (__bf16(*)[208])smem;
#pragma unroll
    for (int i = 0; i < 3; ++i)
#pragma unroll
        for (int r = 0; r < 4; ++r)
            obuf[mt * 16 + lg * 4 + r][(ntb + i) * 16 + lq] = (__bf16)acc[i][r];
    __syncthreads();

    if (w < 4) {
        int mg = w & 1, half = w >> 1;
        size_t qt16 = (size_t)(m0 >> 4) + mg;
        bf16x8 vq = *(const bf16x8*)&obuf[mg * 16 + lq][half * 32 + lg * 8];
        bf16x8 vk = *(const bf16x8*)&obuf[mg * 16 + lq][64 + half * 32 + lg * 8];
        *(bf16x8*)(qf + ((qt16 * 2 + half) * 64 + lane) * 8) = vq;
        *(bf16x8*)(kf + ((qt16 * 2 + half) * 64 + lane) * 8) = vk;
    } else {
        int ntv = w - 4;
        bf16x8 vv;
#pragma unroll
        for (int j = 0; j < 8; ++j)
            vv[j] = obuf[lg * 8 + j][128 + ntv * 16 + lq];
        size_t kt32 = (size_t)(m0 >> 5);
        *(bf16x8*)(vf + ((kt32 * 4 + ntv) * 64 + lane) * 8) = vv;
    }
}

// ---------------------------------------------------------------------------
// Kernel 3: causal flash attention (r8-exact). 512 blocks x 8 waves; wave-
// paired Q32; swapped QK^T; KVBLK=64; defer-max; V-prefetch; flash-combine.
// ---------------------------------------------------------------------------
__global__ __launch_bounds__(512, 4) void attn_kernel(const __bf16* __restrict__ qf,
                                                      const __bf16* __restrict__ kf,
                                                      const __bf16* __restrict__ vf,
                                                      float* __restrict__ out) {
    __shared__ float olds[8][16][64];
    __shared__ float mlds[8][16], llds[8][16];
    __shared__ __align__(16) __bf16 plds[8][16 * 72];

    int w    = threadIdx.x >> 6;
    int lane = threadIdx.x & 63;
    int lq = lane & 15, lg = lane >> 4;

    int b  = blockIdx.x & 7;
    int q0 = (63 - (blockIdx.x >> 3)) * 32;
    int qs = w >> 2;
    int wk = w & 3;
    int qt = q0 + qs * 16;

    size_t qbase = ((size_t)b * 128 + (qt >> 4)) * 2;
    bf16x8 aq0 = *(const bf16x8*)(qf + ((qbase + 0) * 64 + lane) * 8);
    bf16x8 aq1 = *(const bf16x8*)(qf + ((qbase + 1) * 64 + lane) * 8);

    f32x4 o[4];
#pragma unroll
    for (int nt = 0; nt < 4; ++nt) o[nt] = (f32x4)0.0f;
    float m_s = -1e30f, l_s = 0.f;

    __bf16* pw = &plds[w][0];

    int ntiles = (qt + 79) >> 6;
    for (int kt = wk; kt < ntiles; kt += 4) {
        int s0 = kt * 64;
        f32x4 s[4];
        __builtin_amdgcn_s_setprio(1);
#pragma unroll
        for (int ct = 0; ct < 4; ++ct) {
            size_t kbase = ((size_t)b * 128 + (s0 >> 4) + ct) * 2;
            bf16x8 k0 = *(const bf16x8*)(kf + ((kbase + 0) * 64 + lane) * 8);
            bf16x8 k1 = *(const bf16x8*)(kf + ((kbase + 1) * 64 + lane) * 8);
            f32x4 a = (f32x4)0.0f;
            a = __builtin_amdgcn_mfma_f32_16x16x32_bf16(k0, aq0, a, 0, 0, 0);
            a = __builtin_amdgcn_mfma_f32_16x16x32_bf16(k1, aq1, a, 0, 0, 0);
            s[ct] = a;
        }
        __builtin_amdgcn_s_setprio(0);
        if (s0 + 63 > qt) {
#pragma unroll
            for (int ct = 0; ct < 4; ++ct)
#pragma unroll
                for (int r = 0; r < 4; ++r)
                    if (s0 + ct * 16 + lg * 4 + r > qt + lq) s[ct][r] = -1e30f;
        }
        bf16x8 bv[2][4];
#pragma unroll
        for (int ks = 0; ks < 2; ++ks)
#pragma unroll
            for (int nt = 0; nt < 4; ++nt)
                bv[ks][nt] = *(const bf16x8*)(vf +
                    (((size_t)(b * 64 + (s0 >> 5) + ks) * 4 + nt) * 64 + lane) * 8);
        float pm = -1e30f;
#pragma unroll
        for (int ct = 0; ct < 4; ++ct)
#pragma unroll
            for (int r = 0; r < 4; ++r) pm = fmaxf(pm, s[ct][r]);
        pm = fmaxf(pm, __shfl_xor(pm, 16));
        pm = fmaxf(pm, __shfl_xor(pm, 32));
        bool need = __any(pm > m_s);
        float al = 1.0f;
        if (need) {
            float mn = fmaxf(m_s, pm);
            al = __expf(m_s - mn);
            m_s = mn;
        }
        float rs = 0.f;
        f32x4 p[4];
#pragma unroll
        for (int ct = 0; ct < 4; ++ct)
#pragma unroll
            for (int r = 0; r < 4; ++r) {
                p[ct][r] = __expf(s[ct][r] - m_s);
                rs += p[ct][r];
            }
        rs += __shfl_xor(rs, 16);
        rs += __shfl_xor(rs, 32);
        if (need) {
            l_s = l_s * al + rs;
            float alr[4];
#pragma unroll
            for (int r = 0; r < 4; ++r) alr[r] = __shfl(al, lg * 4 + r);
#pragma unroll
            for (int nt = 0; nt < 4; ++nt)
#pragma unroll
                for (int r = 0; r < 4; ++r) o[nt][r] *= alr[r];
        } else {
            l_s += rs;
        }
#pragma unroll
        for (int ct = 0; ct < 4; ++ct) {
            bf16x4 qv;
#pragma unroll
            for (int r = 0; r < 4; ++r) qv[r] = (__bf16)p[ct][r];
            *(bf16x4*)&pw[lq * 72 + ct * 16 + lg * 4] = qv;
        }
        asm volatile("" ::: "memory");
        bf16x8 pa0 = *(const bf16x8*)&pw[lq * 72 + lg * 8];
        bf16x8 pa1 = *(const bf16x8*)&pw[lq * 72 + 32 + lg * 8];
        __builtin_amdgcn_s_setprio(1);
#pragma unroll
        for (int nt = 0; nt < 4; ++nt) {
            o[nt] = __builtin_amdgcn_mfma_f32_16x16x32_bf16(pa0, bv[0][nt], o[nt], 0, 0, 0);
            o[nt] = __builtin_amdgcn_mfma_f32_16x16x32_bf16(pa1, bv[1][nt], o[nt], 0, 0, 0);
        }
        __builtin_amdgcn_s_setprio(0);
    }

    asm volatile("" ::: "memory");
#pragma unroll
    for (int nt = 0; nt < 4; ++nt)
#pragma unroll
        for (int r = 0; r < 4; ++r)
            olds[w][lg * 4 + r][nt * 16 + lq] = o[nt][r];
    if (lg == 0) {
        mlds[w][lq] = m_s;
        llds[w][lq] = l_s;
    }
    __syncthreads();

    int row = threadIdx.x >> 4;
    int c4  = (threadIdx.x & 15) * 4;
    int wb  = (row >> 4) * 4;
    int r16 = row & 15;
    float M = -1e30f;
#pragma unroll
    for (int w2 = 0; w2 < 4; ++w2) M = fmaxf(M, mlds[wb + w2][r16]);
    float L = 0.f;
    f32x4 oa = (f32x4)0.0f;
#pragma unroll
    for (int w2 = 0; w2 < 4; ++w2) {
        float sc = __expf(mlds[wb + w2][r16] - M);
        L += sc * llds[wb + w2][r16];
        const float* op = &olds[wb + w2][r16][c4];
#pragma unroll
        for (int j = 0; j < 4; ++j) oa[j] += sc * op[j];
    }
    float inv = 1.0f / L;
    float4 st;
    st.x = oa[0] * inv; st.y = oa[1] * inv; st.z = oa[2] * inv; st.w = oa[3] * inv;
    *(float4*)(out + ((size_t)b * T_ + q0 + row) * HS_ + c4) = st;
}

extern "C" void kernel_launch(void* const* d_in, const int* in_sizes, int n_in,
                              void* d_out, int out_size, void* d_ws, size_t ws_size,
                              hipStream_t stream) {
    const float* x  = (const float*)d_in[0];
    const float* Wq = (const float*)d_in[1];
    const float* Wk = (const float*)d_in[2];
    const float* Wv = (const float*)d_in[3];
    char* ws = (char*)d_ws;
    __bf16* wt = (__bf16*)ws;                     // 393216 B
    __bf16* qf = (__bf16*)(ws + 393216);          // 2 MB
    __bf16* kf = (__bf16*)(ws + 2490368);         // 2 MB
    __bf16* vf = (__bf16*)(ws + 4587520);         // 2 MB
    float* out = (float*)d_out;

    wt_kernel<<<dim3(48), dim3(256), 0, stream>>>(Wq, Wk, Wv, wt);
    qkv_kernel<<<dim3(512), dim3(512), 0, stream>>>(x, wt, qf, kf, vf);
    attn_kernel<<<dim3(512), dim3(512), 0, stream>>>(qf, kf, vf, out);
}